// Round 1
// baseline (285.079 us; speedup 1.0000x reference)
//
#include <hip/hip_runtime.h>

#define NCLS 8
#define NMAPS 4
#define NCH 2048
#define HW 196
#define NB 64
#define NOUT 48          // 32 downconv rows + 8 fc2 rows (cols 2048..4095) + 8 fc1 rows (cols 0..2047)
#define NCHUNK 8
#define CPC (NCH / NCHUNK)  // 256 channels per chunk

// ---------------------------------------------------------------------------
// Kernel 0: build transposed combined weight WcT[c][o]  (2048 x 48)
//   o in [0,32):  down_w[o][c]
//   o in [32,40): fc_w[o-32][2048 + c]   (weights hitting prod = sal*x)
//   o in [40,48): fc_w[o-40][c]          (weights hitting x_ori)
// Contiguous 48 floats per channel -> scalar-load friendly in conv48.
// ---------------------------------------------------------------------------
__global__ void build_wct(const float* __restrict__ down_w,
                          const float* __restrict__ fc_w,
                          float* __restrict__ wct) {
    int i = blockIdx.x * 256 + threadIdx.x;
    if (i >= NCH * NOUT) return;
    int c = i / NOUT, o = i % NOUT;
    float v;
    if (o < 32)      v = down_w[o * NCH + c];
    else if (o < 40) v = fc_w[(o - 32) * (2 * NCH) + NCH + c];
    else             v = fc_w[(o - 40) * (2 * NCH) + c];
    wct[c * NOUT + o] = v;
}

// ---------------------------------------------------------------------------
// Kernel 1: fused 48-row GEMM over x, chunked along channels.
//   part[b][chunk][o][p] = sum_{c in chunk} WcT[c][o] * x[b][c][p]
// lane = spatial position p (coalesced row reads), 48 fp32 accumulators.
// ---------------------------------------------------------------------------
__global__ __launch_bounds__(256) void conv48(const float* __restrict__ x,
                                              const float* __restrict__ wct,
                                              float* __restrict__ part) {
    const int b = blockIdx.y;
    const int chunk = blockIdx.x;
    const int p = threadIdx.x;
    float acc[NOUT];
#pragma unroll
    for (int o = 0; o < NOUT; ++o) acc[o] = 0.f;

    const float* xb = x + ((size_t)b * NCH + (size_t)chunk * CPC) * HW;
    const float* wb = wct + (size_t)chunk * CPC * NOUT;
    const bool act = (p < HW);

#pragma unroll 4
    for (int c = 0; c < CPC; ++c) {
        float xv = act ? xb[c * HW + p] : 0.f;
        const float* w = wb + c * NOUT;   // uniform address -> scalar loads
#pragma unroll
        for (int o = 0; o < NOUT; ++o)
            acc[o] = fmaf(w[o], xv, acc[o]);
    }

    if (act) {
        float* dst = part + ((size_t)(b * NCHUNK + chunk) * NOUT) * HW + p;
#pragma unroll
        for (int o = 0; o < NOUT; ++o) dst[o * HW] = acc[o];
    }
}

// ---------------------------------------------------------------------------
// Kernel 2: per-batch epilogue. Reduce chunk partials, then:
//   gmp -> scores -> log_softmax (output 0)
//   sal[p] = (1/32) sum_k xo[k] * (sum_m xc[4k+m][p])
//   logits2[j] = (sum_p z[j][p] + sum_p sal[p]*y[j][p])/196 + fc_b[j]
//   log_softmax (output 1)
// ---------------------------------------------------------------------------
__global__ __launch_bounds__(256) void finish(const float* __restrict__ part,
                                              const float* __restrict__ down_b,
                                              const float* __restrict__ fc_b,
                                              float* __restrict__ out) {
    const int b = blockIdx.x;
    const int tid = threadIdx.x;
    __shared__ float T[NOUT * HW];   // 48*196*4 = 37632 B
    __shared__ float gmpS[32];
    __shared__ float scoreS[8];
    __shared__ float xoS[8];
    __shared__ float salS[HW];
    __shared__ float logitS[8];

    // reduce partials over chunks
    if (tid < HW) {
        const float* src = part + (size_t)b * NCHUNK * NOUT * HW + tid;
#pragma unroll
        for (int o = 0; o < NOUT; ++o) {
            float s = 0.f;
#pragma unroll
            for (int ch = 0; ch < NCHUNK; ++ch)
                s += src[(ch * NOUT + o) * HW];
            T[o * HW + tid] = s;
        }
    }
    __syncthreads();

    // global max pool over 14x14 for the 32 downconv rows (+bias commutes past max)
    if (tid < 32) {
        float m = -1e30f;
        for (int p = 0; p < HW; ++p) m = fmaxf(m, T[tid * HW + p]);
        gmpS[tid] = m + down_b[tid];
    }
    __syncthreads();

    // class-wise pool (mean over 4 maps) -> scores
    if (tid < 8)
        scoreS[tid] = 0.25f * (gmpS[4 * tid] + gmpS[4 * tid + 1] +
                               gmpS[4 * tid + 2] + gmpS[4 * tid + 3]);
    __syncthreads();

    // log_softmax over 8 classes -> output 0
    if (tid < 8) {
        float m = -1e30f;
        for (int k = 0; k < 8; ++k) m = fmaxf(m, scoreS[k]);
        float se = 0.f;
        for (int k = 0; k < 8; ++k) se += expf(scoreS[k] - m);
        float xo = scoreS[tid] - m - logf(se);
        xoS[tid] = xo;
        out[b * 8 + tid] = xo;
    }
    __syncthreads();

    // saliency map
    if (tid < HW) {
        float s = 0.f;
#pragma unroll
        for (int k = 0; k < 8; ++k) {
            float bs = down_b[4 * k] + down_b[4 * k + 1] +
                       down_b[4 * k + 2] + down_b[4 * k + 3];
            float rs = T[(4 * k) * HW + tid] + T[(4 * k + 1) * HW + tid] +
                       T[(4 * k + 2) * HW + tid] + T[(4 * k + 3) * HW + tid] + bs;
            s += xoS[k] * rs;
        }
        salS[tid] = s * (1.f / 32.f);
    }
    __syncthreads();

    // second logits: fc1 part (z rows, plain mean) + fc2 part (sal-weighted y rows)
    if (tid < 8) {
        float t1 = 0.f, t2 = 0.f;
        for (int p = 0; p < HW; ++p) {
            t1 += T[(40 + tid) * HW + p];
            t2 += salS[p] * T[(32 + tid) * HW + p];
        }
        logitS[tid] = (t1 + t2) * (1.f / 196.f) + fc_b[tid];
    }
    __syncthreads();

    // log_softmax -> output 1
    if (tid < 8) {
        float m = -1e30f;
        for (int k = 0; k < 8; ++k) m = fmaxf(m, logitS[k]);
        float se = 0.f;
        for (int k = 0; k < 8; ++k) se += expf(logitS[k] - m);
        out[NB * 8 + b * 8 + tid] = logitS[tid] - m - logf(se);
    }
}

extern "C" void kernel_launch(void* const* d_in, const int* in_sizes, int n_in,
                              void* d_out, int out_size, void* d_ws, size_t ws_size,
                              hipStream_t stream) {
    const float* x      = (const float*)d_in[0];
    const float* down_w = (const float*)d_in[1];
    const float* down_b = (const float*)d_in[2];
    const float* fc_w   = (const float*)d_in[3];
    const float* fc_b   = (const float*)d_in[4];
    float* out = (float*)d_out;

    float* wct  = (float*)d_ws;              // 2048*48 floats = 384 KiB
    float* part = wct + NCH * NOUT;          // 64*8*48*196 floats = ~18.4 MiB

    build_wct<<<(NCH * NOUT + 255) / 256, 256, 0, stream>>>(down_w, fc_w, wct);
    conv48<<<dim3(NCHUNK, NB), 256, 0, stream>>>(x, wct, part);
    finish<<<NB, 256, 0, stream>>>(part, down_b, fc_b, out);
}

// Round 2
// 205.127 us; speedup vs baseline: 1.3898x; 1.3898x over previous
//
#include <hip/hip_runtime.h>

#define NCLS 8
#define NMAPS 4
#define NCH 2048
#define HW 196
#define NB 64
#define NOUT 48   // 32 downconv rows + 8 fc2 rows (cols 2048..4095) + 8 fc1 rows (cols 0..2047)
#define PF 8      // software-pipeline prefetch depth

// ---------------------------------------------------------------------------
// Kernel 0: build transposed combined weight WcT[c][o]  (2048 x 48)
// ---------------------------------------------------------------------------
__global__ void build_wct(const float* __restrict__ down_w,
                          const float* __restrict__ fc_w,
                          float* __restrict__ wct) {
    int i = blockIdx.x * 256 + threadIdx.x;
    if (i >= NCH * NOUT) return;
    int c = i / NOUT, o = i % NOUT;
    float v;
    if (o < 32)      v = down_w[o * NCH + c];
    else if (o < 40) v = fc_w[(o - 32) * (2 * NCH) + NCH + c];
    else             v = fc_w[(o - 40) * (2 * NCH) + c];
    wct[c * NOUT + o] = v;
}

// ---------------------------------------------------------------------------
// Kernel 1: fused 48-row GEMM over x, chunked along channels.
// Manual software pipeline (depth PF) + per-group asm barrier to prevent the
// compiler from interchanging/fissioning the o-loop (round-1 failure: VGPR=32
// proved it kept 1 accumulator and re-read x 48x from L2 -> 153us).
// ---------------------------------------------------------------------------
__global__ __launch_bounds__(256) void conv48(const float* __restrict__ x,
                                              const float* __restrict__ wct,
                                              float* __restrict__ part,
                                              int cpc, int nchunk) {
    const int b = blockIdx.y;
    const int chunk = blockIdx.x;
    const int p = threadIdx.x;
    const int pp = (p < HW) ? p : (HW - 1);   // keep inactive lanes in-bounds

    float acc[NOUT];
#pragma unroll
    for (int o = 0; o < NOUT; ++o) acc[o] = 0.f;

    const float* xb = x + ((size_t)b * NCH + (size_t)chunk * cpc) * HW + pp;
    const float* wb = wct + (size_t)chunk * cpc * NOUT;

    float xv[PF];
#pragma unroll
    for (int i = 0; i < PF; ++i) xv[i] = xb[i * HW];

    int c0 = 0;
    for (; c0 + 2 * PF <= cpc; c0 += PF) {
        float xn[PF];
#pragma unroll
        for (int i = 0; i < PF; ++i) xn[i] = xb[(c0 + PF + i) * HW];
#pragma unroll
        for (int i = 0; i < PF; ++i) {
            const float* w = wb + (c0 + i) * NOUT;   // uniform -> s_load
#pragma unroll
            for (int o = 0; o < NOUT; ++o)
                acc[o] = fmaf(w[o], xv[i], acc[o]);
        }
#pragma unroll
        for (int i = 0; i < PF; ++i) xv[i] = xn[i];
        __asm__ volatile("" ::: "memory");   // block loop interchange/fission
    }
    // final group (already prefetched in xv)
#pragma unroll
    for (int i = 0; i < PF; ++i) {
        const float* w = wb + (c0 + i) * NOUT;
#pragma unroll
        for (int o = 0; o < NOUT; ++o)
            acc[o] = fmaf(w[o], xv[i], acc[o]);
    }

    if (p < HW) {
        float* dst = part + ((size_t)(b * nchunk + chunk) * NOUT) * HW + p;
#pragma unroll
        for (int o = 0; o < NOUT; ++o) dst[o * HW] = acc[o];
    }
}

// ---------------------------------------------------------------------------
// Kernel 2: reduce chunk partials -> T[b][o][p]  (fully parallel, coalesced)
// ---------------------------------------------------------------------------
__global__ __launch_bounds__(256) void reduce_part(const float* __restrict__ part,
                                                   float* __restrict__ T,
                                                   int nchunk) {
    int idx = blockIdx.x * 256 + threadIdx.x;
    if (idx >= NB * NOUT * HW) return;
    int b = idx / (NOUT * HW);
    int rem = idx - b * NOUT * HW;
    const float* src = part + (size_t)b * nchunk * NOUT * HW + rem;
    float s = 0.f;
    for (int ch = 0; ch < nchunk; ++ch)
        s += src[(size_t)ch * NOUT * HW];
    T[idx] = s;
}

// ---------------------------------------------------------------------------
// Kernel 3: per-batch epilogue on the reduced 48x196 slab (2.4 MB total).
// ---------------------------------------------------------------------------
__global__ __launch_bounds__(256) void finish(const float* __restrict__ T,
                                              const float* __restrict__ down_b,
                                              const float* __restrict__ fc_b,
                                              float* __restrict__ out) {
    const int b = blockIdx.x;
    const int tid = threadIdx.x;
    __shared__ float Ts[NOUT * HW];   // 37632 B
    __shared__ float gmpS[32];
    __shared__ float scoreS[8];
    __shared__ float xoS[8];
    __shared__ float salS[HW];
    __shared__ float logitS[8];

    // stage slab into LDS with float4 (9408 floats = 2352 float4)
    {
        const float4* src = (const float4*)(T + (size_t)b * NOUT * HW);
        float4* dst = (float4*)Ts;
        for (int i = tid; i < NOUT * HW / 4; i += 256) dst[i] = src[i];
    }
    __syncthreads();

    // global max pool for the 32 downconv rows (+bias commutes past max)
    if (tid < 32) {
        float m = -1e30f;
        for (int p = 0; p < HW; ++p) m = fmaxf(m, Ts[tid * HW + p]);
        gmpS[tid] = m + down_b[tid];
    }
    __syncthreads();

    if (tid < 8)
        scoreS[tid] = 0.25f * (gmpS[4 * tid] + gmpS[4 * tid + 1] +
                               gmpS[4 * tid + 2] + gmpS[4 * tid + 3]);
    __syncthreads();

    // log_softmax over 8 classes -> output 0
    if (tid < 8) {
        float m = -1e30f;
        for (int k = 0; k < 8; ++k) m = fmaxf(m, scoreS[k]);
        float se = 0.f;
        for (int k = 0; k < 8; ++k) se += expf(scoreS[k] - m);
        float xo = scoreS[tid] - m - logf(se);
        xoS[tid] = xo;
        out[b * 8 + tid] = xo;
    }
    __syncthreads();

    // saliency map
    if (tid < HW) {
        float s = 0.f;
#pragma unroll
        for (int k = 0; k < 8; ++k) {
            float bs = down_b[4 * k] + down_b[4 * k + 1] +
                       down_b[4 * k + 2] + down_b[4 * k + 3];
            float rs = Ts[(4 * k) * HW + tid] + Ts[(4 * k + 1) * HW + tid] +
                       Ts[(4 * k + 2) * HW + tid] + Ts[(4 * k + 3) * HW + tid] + bs;
            s += xoS[k] * rs;
        }
        salS[tid] = s * (1.f / 32.f);
    }
    __syncthreads();

    // second logits: fc1 rows (plain mean) + sal-weighted fc2 rows
    if (tid < 8) {
        float t1 = 0.f, t2 = 0.f;
        for (int p = 0; p < HW; ++p) {
            t1 += Ts[(40 + tid) * HW + p];
            t2 += salS[p] * Ts[(32 + tid) * HW + p];
        }
        logitS[tid] = (t1 + t2) * (1.f / 196.f) + fc_b[tid];
    }
    __syncthreads();

    // log_softmax -> output 1
    if (tid < 8) {
        float m = -1e30f;
        for (int k = 0; k < 8; ++k) m = fmaxf(m, logitS[k]);
        float se = 0.f;
        for (int k = 0; k < 8; ++k) se += expf(logitS[k] - m);
        out[NB * 8 + b * 8 + tid] = logitS[tid] - m - logf(se);
    }
}

extern "C" void kernel_launch(void* const* d_in, const int* in_sizes, int n_in,
                              void* d_out, int out_size, void* d_ws, size_t ws_size,
                              hipStream_t stream) {
    const float* x      = (const float*)d_in[0];
    const float* down_w = (const float*)d_in[1];
    const float* down_b = (const float*)d_in[2];
    const float* fc_w   = (const float*)d_in[3];
    const float* fc_b   = (const float*)d_in[4];
    float* out = (float*)d_out;

    float* wct  = (float*)d_ws;                    // 2048*48 = 384 KiB
    float* T    = wct + NCH * NOUT;                // 64*48*196 = 2.3 MiB
    float* part = T + NB * NOUT * HW;              // 64*nchunk*48*196 floats

    // pick chunk count by available workspace (16 -> 4 blocks/CU occupancy)
    size_t base_bytes = ((size_t)NCH * NOUT + (size_t)NB * NOUT * HW) * 4;
    int nchunk = 16;
    if (ws_size < base_bytes + (size_t)NB * 16 * NOUT * HW * 4) nchunk = 8;
    int cpc = NCH / nchunk;

    build_wct<<<(NCH * NOUT + 255) / 256, 256, 0, stream>>>(down_w, fc_w, wct);
    conv48<<<dim3(nchunk, NB), 256, 0, stream>>>(x, wct, part, cpc, nchunk);
    reduce_part<<<(NB * NOUT * HW + 255) / 256, 256, 0, stream>>>(part, T, nchunk);
    finish<<<NB, 256, 0, stream>>>(T, down_b, fc_b, out);
}

// Round 3
// 202.564 us; speedup vs baseline: 1.4074x; 1.0127x over previous
//
#include <hip/hip_runtime.h>

#define NCLS 8
#define NMAPS 4
#define NCH 2048
#define HW 196
#define NB 64
#define NOUT 48   // 32 downconv rows + 8 fc2 rows (cols 2048..4095) + 8 fc1 rows (cols 0..2047)
#define OG 3      // output groups
#define OPG 16    // outputs per group (16 accs/thread -> stays in arch VGPRs, no AGPR shuffle)
#define PF 8      // software-pipeline prefetch depth

// ---------------------------------------------------------------------------
// Kernel 0: build transposed combined weight WcT[c][o] (2048 x 48).
// Reads coalesced (c fast within a wave), writes scattered (tiny tensor, L2
// absorbs partial-line writes).
// ---------------------------------------------------------------------------
__global__ void build_wct(const float* __restrict__ down_w,
                          const float* __restrict__ fc_w,
                          float* __restrict__ wct) {
    int i = blockIdx.x * 256 + threadIdx.x;   // 48*2048 total
    if (i >= NCH * NOUT) return;
    int o = i >> 11;          // i / 2048  (wave-uniform)
    int c = i & (NCH - 1);    // i % 2048  (coalesced)
    float v;
    if (o < 32)      v = down_w[o * NCH + c];
    else if (o < 40) v = fc_w[(o - 32) * (2 * NCH) + NCH + c];
    else             v = fc_w[(o - 40) * (2 * NCH) + c];
    wct[c * NOUT + o] = v;
}

// ---------------------------------------------------------------------------
// Kernel 1: fused 48-row GEMM over x, split (channel-chunk x output-group).
// 16 accumulators/thread: round-2 postmortem showed 48 accs get demoted to
// AGPRs (VGPR=40) -> v_accvgpr_read/fmac/write = 3 VALU per FMA = 61.4us
// (matched observed). 16 accs fit in arch VGPRs -> 1 inst/FMA.
// Manual pipeline + asm barrier still blocks loop interchange (round-1 bug).
// ---------------------------------------------------------------------------
__global__ __launch_bounds__(256) void conv48(const float* __restrict__ x,
                                              const float* __restrict__ wct,
                                              float* __restrict__ part,
                                              int cpc, int nchunk) {
    const int b = blockIdx.y;
    const int chunk = blockIdx.x / OG;
    const int og = blockIdx.x - chunk * OG;
    const int p = threadIdx.x;
    const int pp = (p < HW) ? p : (HW - 1);   // keep inactive lanes in-bounds

    float acc[OPG];
#pragma unroll
    for (int o = 0; o < OPG; ++o) acc[o] = 0.f;

    const float* xb = x + ((size_t)b * NCH + (size_t)chunk * cpc) * HW + pp;
    const float* wb = wct + (size_t)chunk * cpc * NOUT + og * OPG;

    float xv[PF];
#pragma unroll
    for (int i = 0; i < PF; ++i) xv[i] = xb[i * HW];

    int c0 = 0;
    for (; c0 + 2 * PF <= cpc; c0 += PF) {
        float xn[PF];
#pragma unroll
        for (int i = 0; i < PF; ++i) xn[i] = xb[(c0 + PF + i) * HW];
#pragma unroll
        for (int i = 0; i < PF; ++i) {
            const float* w = wb + (c0 + i) * NOUT;   // uniform -> s_load
#pragma unroll
            for (int o = 0; o < OPG; ++o)
                acc[o] = fmaf(w[o], xv[i], acc[o]);
        }
#pragma unroll
        for (int i = 0; i < PF; ++i) xv[i] = xn[i];
        __asm__ volatile("" ::: "memory");   // block loop interchange/fission
    }
    // final group (already prefetched in xv)
#pragma unroll
    for (int i = 0; i < PF; ++i) {
        const float* w = wb + (c0 + i) * NOUT;
#pragma unroll
        for (int o = 0; o < OPG; ++o)
            acc[o] = fmaf(w[o], xv[i], acc[o]);
    }

    if (p < HW) {
        float* dst = part + ((size_t)(b * nchunk + chunk) * NOUT + og * OPG) * HW + p;
#pragma unroll
        for (int o = 0; o < OPG; ++o) dst[o * HW] = acc[o];
    }
}

// ---------------------------------------------------------------------------
// Kernel 2: per-batch fused chunk-reduce + epilogue.
// Reduce nchunk partial slabs (float4, coalesced) into LDS, then:
//   gmp -> scores -> log_softmax (out 0)
//   sal[p] = (1/32) sum_k xo[k] * class_sum_k[p]
//   logits2[j] = (sum_p z[j][p] + sum_p sal[p]*y[j][p])/196 + fc_b[j] -> out 1
// ---------------------------------------------------------------------------
__global__ __launch_bounds__(256) void finish(const float* __restrict__ part,
                                              const float* __restrict__ down_b,
                                              const float* __restrict__ fc_b,
                                              float* __restrict__ out,
                                              int nchunk) {
    const int b = blockIdx.x;
    const int tid = threadIdx.x;
    __shared__ float Ts[NOUT * HW];   // 37632 B
    __shared__ float gmpS[32];
    __shared__ float scoreS[8];
    __shared__ float xoS[8];
    __shared__ float salS[HW];
    __shared__ float logitS[8];

    // fused reduce over chunks, float4 coalesced
    {
        const float4* src = (const float4*)(part + (size_t)b * nchunk * NOUT * HW);
        float4* dst = (float4*)Ts;
        const int n4 = NOUT * HW / 4;          // 2352
        for (int i = tid; i < n4; i += 256) {
            float4 s = src[i];
            for (int ch = 1; ch < nchunk; ++ch) {
                float4 v = src[(size_t)ch * n4 + i];
                s.x += v.x; s.y += v.y; s.z += v.z; s.w += v.w;
            }
            dst[i] = s;
        }
    }
    __syncthreads();

    // global max pool for the 32 downconv rows (+bias commutes past max)
    if (tid < 32) {
        float m = -1e30f;
        for (int p = 0; p < HW; ++p) m = fmaxf(m, Ts[tid * HW + p]);
        gmpS[tid] = m + down_b[tid];
    }
    __syncthreads();

    if (tid < 8)
        scoreS[tid] = 0.25f * (gmpS[4 * tid] + gmpS[4 * tid + 1] +
                               gmpS[4 * tid + 2] + gmpS[4 * tid + 3]);
    __syncthreads();

    // log_softmax over 8 classes -> output 0
    if (tid < 8) {
        float m = -1e30f;
        for (int k = 0; k < 8; ++k) m = fmaxf(m, scoreS[k]);
        float se = 0.f;
        for (int k = 0; k < 8; ++k) se += expf(scoreS[k] - m);
        float xo = scoreS[tid] - m - logf(se);
        xoS[tid] = xo;
        out[b * 8 + tid] = xo;
    }
    __syncthreads();

    // saliency map
    if (tid < HW) {
        float s = 0.f;
#pragma unroll
        for (int k = 0; k < 8; ++k) {
            float bs = down_b[4 * k] + down_b[4 * k + 1] +
                       down_b[4 * k + 2] + down_b[4 * k + 3];
            float rs = Ts[(4 * k) * HW + tid] + Ts[(4 * k + 1) * HW + tid] +
                       Ts[(4 * k + 2) * HW + tid] + Ts[(4 * k + 3) * HW + tid] + bs;
            s += xoS[k] * rs;
        }
        salS[tid] = s * (1.f / 32.f);
    }
    __syncthreads();

    // second logits: fc1 rows (plain mean) + sal-weighted fc2 rows
    if (tid < 8) {
        float t1 = 0.f, t2 = 0.f;
        for (int p = 0; p < HW; ++p) {
            t1 += Ts[(40 + tid) * HW + p];
            t2 += salS[p] * Ts[(32 + tid) * HW + p];
        }
        logitS[tid] = (t1 + t2) * (1.f / 196.f) + fc_b[tid];
    }
    __syncthreads();

    // log_softmax -> output 1
    if (tid < 8) {
        float m = -1e30f;
        for (int k = 0; k < 8; ++k) m = fmaxf(m, logitS[k]);
        float se = 0.f;
        for (int k = 0; k < 8; ++k) se += expf(logitS[k] - m);
        out[NB * 8 + b * 8 + tid] = logitS[tid] - m - logf(se);
    }
}

extern "C" void kernel_launch(void* const* d_in, const int* in_sizes, int n_in,
                              void* d_out, int out_size, void* d_ws, size_t ws_size,
                              hipStream_t stream) {
    const float* x      = (const float*)d_in[0];
    const float* down_w = (const float*)d_in[1];
    const float* down_b = (const float*)d_in[2];
    const float* fc_w   = (const float*)d_in[3];
    const float* fc_b   = (const float*)d_in[4];
    float* out = (float*)d_out;

    float* wct  = (float*)d_ws;            // 2048*48 = 384 KiB
    float* part = wct + NCH * NOUT;        // 64*nchunk*48*196 floats

    // nchunk=8 -> part 19.3 MiB (ws proven >= 41 MiB in round 2); fallback 4.
    size_t base_bytes = (size_t)NCH * NOUT * 4;
    int nchunk = 8;
    if (ws_size < base_bytes + (size_t)NB * 8 * NOUT * HW * 4) nchunk = 4;
    int cpc = NCH / nchunk;

    build_wct<<<(NCH * NOUT + 255) / 256, 256, 0, stream>>>(down_w, fc_w, wct);
    conv48<<<dim3(nchunk * OG, NB), 256, 0, stream>>>(x, wct, part, cpc, nchunk);
    finish<<<NB, 256, 0, stream>>>(part, down_b, fc_b, out, nchunk);
}